// Round 4
// baseline (593.751 us; speedup 1.0000x reference)
//
#include <hip/hip_runtime.h>

#define SEQ 4096
#define CDN 0.35355339059327379f   // 64^(-1/4)
#define DIAGC 0.0625f              // 0.5 * CDN^2
#define KEPS 1e-4f

typedef _Float16 f16;
typedef f16 f16x8 __attribute__((ext_vector_type(8)));
typedef f16 f16x4 __attribute__((ext_vector_type(4)));
typedef float f32x4 __attribute__((ext_vector_type(4)));

#define MFMA16(a, b, c) __builtin_amdgcn_mfma_f32_16x16x32_f16(a, b, c, 0, 0, 0)

// proj LDS: 256 rows x stride 72 f16 (144 B rows: 16B-aligned b128 reads, <=2-way banks)
#define PSTR 72

__device__ __forceinline__ void stage_proj(const float* __restrict__ proj, f16* plds) {
  int t = threadIdx.x;
  int mrow = t >> 2;
  int cb = (t & 3) * 16;
#pragma unroll
  for (int p = 0; p < 4; ++p) {
    int m = mrow + p * 64;
    const float4* src = (const float4*)(proj + m * 64 + cb);
    f16* dst = plds + m * PSTR + cb;
#pragma unroll
    for (int i = 0; i < 4; ++i) {
      float4 v = src[i];
      f16x4 h = {(f16)v.x, (f16)v.y, (f16)v.z, (f16)v.w};
      *(f16x4*)(dst + i * 4) = h;
    }
  }
}

// fragment of proj rows [16*mtile + (lane&15)], d = ks*32 + (lane>>4)*8 .. +7
__device__ __forceinline__ f16x8 proj_frag(const f16* plds, int mtile, int ks, int lane) {
  int m = (lane & 15) + 16 * mtile;
  return *(const f16x8*)(plds + m * PSTR + ks * 32 + (lane >> 4) * 8);
}

// row fragment of q/k: row = base_row + (lane&15), d = ks*32 + (lane>>4)*8 .. +7, scaled by CDN
__device__ __forceinline__ f16x8 row_frag(const float* __restrict__ base, int lane, int ks, float& sq) {
  const float4* p = (const float4*)(base + (size_t)(lane & 15) * 64 + ks * 32 + (lane >> 4) * 8);
  float4 a = p[0], b = p[1];
  sq += a.x*a.x + a.y*a.y + a.z*a.z + a.w*a.w + b.x*b.x + b.y*b.y + b.z*b.z + b.w*b.w;
  f16x8 r = {(f16)(a.x*CDN), (f16)(a.y*CDN), (f16)(a.z*CDN), (f16)(a.w*CDN),
             (f16)(b.x*CDN), (f16)(b.y*CDN), (f16)(b.z*CDN), (f16)(b.w*CDN)};
  return r;
}

// ---------------- K1: per-bh global max of dd_k -> 8 partials per bh ----------------
// LDS = plds only (~37 KB) -> 4 blocks/CU
__global__ __launch_bounds__(256, 4) void k1_stab(
    const float* __restrict__ kk, const float* __restrict__ proj,
    float* __restrict__ ws_stab) {
  __shared__ f16 plds[256 * PSTR];
  __shared__ float wred[4];
  int bh = blockIdx.x >> 3, blk = blockIdx.x & 7;
  stage_proj(proj, plds);
  __syncthreads();
  int w = threadIdx.x >> 6, lane = threadIdx.x & 63;
  const float* kbh = kk + (size_t)bh * SEQ * 64;
  float rmax = -1e30f;
#pragma unroll 1
  for (int it = 0; it < 8; ++it) {
    int n0 = blk * 512 + it * 64 + w * 16;
    float sq = 0.f;
    f16x8 b0 = row_frag(kbh + (size_t)n0 * 64, lane, 0, sq);
    f16x8 b1 = row_frag(kbh + (size_t)n0 * 64, lane, 1, sq);
#pragma unroll
    for (int mt = 0; mt < 16; ++mt) {
      f32x4 acc = {0.f, 0.f, 0.f, 0.f};
      acc = MFMA16(proj_frag(plds, mt, 0, lane), b0, acc);
      acc = MFMA16(proj_frag(plds, mt, 1, lane), b1, acc);
      rmax = fmaxf(rmax, fmaxf(fmaxf(acc[0], acc[1]), fmaxf(acc[2], acc[3])));
    }
  }
#pragma unroll
  for (int m = 1; m < 64; m <<= 1) rmax = fmaxf(rmax, __shfl_xor(rmax, m, 64));
  if (lane == 0) wred[w] = rmax;
  __syncthreads();
  if (threadIdx.x == 0)
    ws_stab[bh * 8 + blk] = fmaxf(fmaxf(wred[0], wred[1]), fmaxf(wred[2], wred[3]));
}

// ---------------- K2: partial context[m][e] + k_cumsum[m]; barrier-free main loop ----
// LDS = plds (36.9 KB) + per-wave transpose buf (5 KB) -> 3 blocks/CU.
// v loaded directly from global into B-fragments (no vt staging, no barriers);
// diag redistributed via shuffles (no diag_s).
__global__ __launch_bounds__(256, 3) void k2_ctx(
    const float* __restrict__ kk, const float* __restrict__ vv,
    const float* __restrict__ proj, const float* __restrict__ ws_stab,
    float* __restrict__ ctx_part, float* __restrict__ kcum_part) {
  __shared__ f16 plds[256 * PSTR];
  __shared__ __align__(16) f16 tbuf[4][16 * 40];  // per-wave [m16][n32+pad] phi transpose
  int bh = blockIdx.x >> 3, s = blockIdx.x & 7;
  stage_proj(proj, plds);
  float stab = -1e30f;
#pragma unroll
  for (int i = 0; i < 8; ++i) stab = fmaxf(stab, ws_stab[bh * 8 + i]);
  int w = threadIdx.x >> 6, lane = threadIdx.x & 63;
  int q4 = lane >> 4, l15 = lane & 15;
  const float* kbh = kk + (size_t)bh * SEQ * 64;
  const float* vbh = vv + (size_t)bh * SEQ * 64;
  f16* tb = &tbuf[w][0];
  f32x4 actx[4][4];
  f32x4 akc[4];
#pragma unroll
  for (int i = 0; i < 4; ++i) {
    akc[i] = (f32x4){0.f, 0.f, 0.f, 0.f};
#pragma unroll
    for (int j = 0; j < 4; ++j) actx[i][j] = (f32x4){0.f, 0.f, 0.f, 0.f};
  }
  f16x8 ones = {(f16)1.f, (f16)1.f, (f16)1.f, (f16)1.f,
                (f16)1.f, (f16)1.f, (f16)1.f, (f16)1.f};
  __syncthreads();  // plds ready — the only barrier
#pragma unroll 1
  for (int it = 0; it < 16; ++it) {
    int n0 = s * 512 + it * 32;
    // v B-fragments: lane (q4,l15) holds v[n0+q4*8+j][l15+16*et], j=0..7
    // per instr: 16 lanes x 4B = 64B segments; 4 waves reuse the same rows via L1
    f16x8 bv[4];
#pragma unroll
    for (int et = 0; et < 4; ++et) {
      const float* vp = vbh + (size_t)(n0 + q4 * 8) * 64 + l15 + 16 * et;
      f16x8 t;
#pragma unroll
      for (int j = 0; j < 8; ++j) t[j] = (f16)vp[(size_t)j * 64];
      bv[et] = t;
    }
    // k row frags (A-operand) + per-row diag
    f16x8 ak[2][2];
    float dg[2];
#pragma unroll
    for (int nt = 0; nt < 2; ++nt) {
      float sq = 0.f;
      ak[nt][0] = row_frag(kbh + (size_t)(n0 + nt * 16) * 64, lane, 0, sq);
      ak[nt][1] = row_frag(kbh + (size_t)(n0 + nt * 16) * 64, lane, 1, sq);
      sq += __shfl_xor(sq, 16, 64);
      sq += __shfl_xor(sq, 32, 64);
      dg[nt] = sq * DIAGC;  // diag of n-local = nt*16 + l15 (valid in every q4 group)
    }
    // redistribute diag: lane (q4,l15) needs diag of n-local = nt*16 + q4*4 + r
    float4 dgv[2];
#pragma unroll
    for (int nt = 0; nt < 2; ++nt) {
      dgv[nt].x = __shfl(dg[nt], q4 * 4 + 0, 64);
      dgv[nt].y = __shfl(dg[nt], q4 * 4 + 1, 64);
      dgv[nt].z = __shfl(dg[nt], q4 * 4 + 2, 64);
      dgv[nt].w = __shfl(dg[nt], q4 * 4 + 3, 64);
    }
    // per m-tile: dd -> phi (C layout) -> per-wave LDS mini-transpose -> A-frag -> MFMA
#pragma unroll
    for (int mtl = 0; mtl < 4; ++mtl) {
      f16x8 bp0 = proj_frag(plds, w * 4 + mtl, 0, lane);
      f16x8 bp1 = proj_frag(plds, w * 4 + mtl, 1, lane);
#pragma unroll
      for (int nt = 0; nt < 2; ++nt) {
        f32x4 acc = {0.f, 0.f, 0.f, 0.f};
        acc = MFMA16(ak[nt][0], bp0, acc);
        acc = MFMA16(ak[nt][1], bp1, acc);
        f16x4 ph;
        ph[0] = (f16)(__expf(acc[0] - dgv[nt].x - stab) + KEPS);
        ph[1] = (f16)(__expf(acc[1] - dgv[nt].y - stab) + KEPS);
        ph[2] = (f16)(__expf(acc[2] - dgv[nt].z - stab) + KEPS);
        ph[3] = (f16)(__expf(acc[3] - dgv[nt].w - stab) + KEPS);
        // phi[m=16*(4w+mtl)+l15][n-local = nt*16+q4*4+r] -> buf[m-local=l15][n-local]
        *(f16x4*)(tb + l15 * 40 + nt * 16 + q4 * 4) = ph;
      }
      // wave-internal write->read (lockstep, no barrier needed)
      f16x8 aph = *(const f16x8*)(tb + l15 * 40 + q4 * 8);
      akc[mtl] = MFMA16(aph, ones, akc[mtl]);  // k_cumsum via ones-vector
#pragma unroll
      for (int et = 0; et < 4; ++et)
        actx[mtl][et] = MFMA16(aph, bv[et], actx[mtl][et]);
    }
  }
  // plain coalesced partial stores
  float* cpart = ctx_part + ((size_t)bh * 8 + s) * 16384;
  float* kcp = kcum_part + ((size_t)bh * 8 + s) * 256;
#pragma unroll 1
  for (int mtl = 0; mtl < 4; ++mtl) {
    int mbase = (w * 4 + mtl) * 16 + q4 * 4;
#pragma unroll
    for (int r = 0; r < 4; ++r) {
#pragma unroll
      for (int et = 0; et < 4; ++et)
        cpart[(size_t)(mbase + r) * 64 + l15 + 16 * et] = actx[mtl][et][r];
    }
    if (l15 == 0) {
#pragma unroll
      for (int r = 0; r < 4; ++r)
        kcp[mbase + r] = akc[mtl][r];
    }
  }
}

// ---------------- K2b: reduce 8 partials -> fp32 kcum + f16 ctxT [e][m] -------------
__global__ __launch_bounds__(256) void k2b_t(
    const float* __restrict__ ctx_part, const float* __restrict__ kcum_part,
    float* __restrict__ ws_kcum, f16* __restrict__ ws_ctxT) {
  __shared__ float tile[64 * 65];  // [m_local][e], stride 65 (conflict-free transpose)
  int bh = blockIdx.x >> 2, qm = blockIdx.x & 3;
  int m0 = qm * 64;
  const float* cp = ctx_part + (size_t)bh * 8 * 16384 + (size_t)m0 * 64;
  int t = threadIdx.x;
#pragma unroll
  for (int i = 0; i < 16; ++i) {
    int idx = t + i * 256;           // idx over [64m x 64e]
    int ml = idx >> 6, e = idx & 63;
    float acc = 0.f;
#pragma unroll
    for (int s = 0; s < 8; ++s) acc += cp[(size_t)s * 16384 + idx];
    tile[ml * 65 + e] = acc;
  }
  if (t < 64) {
    const float* kp = kcum_part + (size_t)bh * 8 * 256 + m0 + t;
    float acc = 0.f;
#pragma unroll
    for (int s = 0; s < 8; ++s) acc += kp[s * 256];
    ws_kcum[bh * 256 + m0 + t] = acc;
  }
  __syncthreads();
  f16* ct = ws_ctxT + (size_t)bh * 16384 + m0;
  int mj = t & 63, eg = t >> 6;
#pragma unroll
  for (int i = 0; i < 16; ++i) {
    int e = eg + i * 4;
    ct[(size_t)e * 256 + mj] = (f16)tile[mj * 65 + e];
  }
}

// ---------------- K3: dd_q -> phi_q -> out = (phi_q @ ctx) / (phi_q . kcum) ----------
// Denominator fused with out-GEMM (accumulate unnormalized, scale at store).
// LDS = plds + per-wave 5 KB buf + kcl -> 3 blocks/CU; loop barrier-free.
__global__ __launch_bounds__(256, 3) void k3_out(
    const float* __restrict__ qq, const float* __restrict__ proj,
    const float* __restrict__ ws_kcum, const f16* __restrict__ ws_ctxT,
    float* __restrict__ out) {
  __shared__ f16 plds[256 * PSTR];
  __shared__ __align__(16) f16 tbuf[4][16 * 40];  // per-wave [n16][m32+pad]
  __shared__ __align__(16) float kcl[256];
  int bh = blockIdx.x >> 4, blk = blockIdx.x & 15;
  stage_proj(proj, plds);
  kcl[threadIdx.x] = ws_kcum[bh * 256 + threadIdx.x];
  __syncthreads();
  int w = threadIdx.x >> 6, lane = threadIdx.x & 63;
  int q4 = lane >> 4, l15 = lane & 15;
  const float* qbh = qq + (size_t)bh * SEQ * 64;
  const f16* ctb = ws_ctxT + (size_t)bh * 16384;
  float* obh = out + (size_t)bh * SEQ * 64;
  f16* tb = &tbuf[w][0];
#pragma unroll 1
  for (int it = 0; it < 4; ++it) {
    int n0 = blk * 256 + w * 64 + it * 16;
    float sq = 0.f;
    f16x8 bq0 = row_frag(qbh + (size_t)n0 * 64, lane, 0, sq);
    f16x8 bq1 = row_frag(qbh + (size_t)n0 * 64, lane, 1, sq);
    sq += __shfl_xor(sq, 16, 64);
    sq += __shfl_xor(sq, 32, 64);
    float diag = sq * DIAGC;  // diag for column n = n0 + l15 (ddT orientation)
    f32x4 dd[16];
#pragma unroll
    for (int mt = 0; mt < 16; ++mt) {
      f32x4 acc = {0.f, 0.f, 0.f, 0.f};
      acc = MFMA16(proj_frag(plds, mt, 0, lane), bq0, acc);
      acc = MFMA16(proj_frag(plds, mt, 1, lane), bq1, acc);
      dd[mt] = acc;  // ddT: row m = 16*mt + 4*q4 + reg, col n = l15
    }
    float st = -1e30f;
#pragma unroll
    for (int mt = 0; mt < 16; ++mt)
      st = fmaxf(st, fmaxf(fmaxf(dd[mt][0], dd[mt][1]), fmaxf(dd[mt][2], dd[mt][3])));
    st = fmaxf(st, __shfl_xor(st, 16, 64));
    st = fmaxf(st, __shfl_xor(st, 32, 64));  // per-query-row max
    float dacc = 0.f;
    f32x4 ao[4];
#pragma unroll
    for (int r = 0; r < 4; ++r) ao[r] = (f32x4){0.f, 0.f, 0.f, 0.f};
#pragma unroll
    for (int ks2 = 0; ks2 < 8; ++ks2) {
#pragma unroll
      for (int half = 0; half < 2; ++half) {
        int mt = ks2 * 2 + half;
        float4 kc = ((const float4*)kcl)[mt * 4 + q4];
        float e0 = __expf(dd[mt][0] - diag - st) + KEPS;
        float e1 = __expf(dd[mt][1] - diag - st) + KEPS;
        float e2 = __expf(dd[mt][2] - diag - st) + KEPS;
        float e3 = __expf(dd[mt][3] - diag - st) + KEPS;
        dacc += e0 * kc.x + e1 * kc.y + e2 * kc.z + e3 * kc.w;
        f16x4 ph;
        ph[0] = (f16)e0; ph[1] = (f16)e1; ph[2] = (f16)e2; ph[3] = (f16)e3;
        // phi[m-chunk-local = 16*half+4*q4+r][n=l15] -> buf[n=l15][m-local]
        *(f16x4*)(tb + l15 * 40 + half * 16 + q4 * 4) = ph;
      }
      // wave-internal write->read; B[k=m-local=q4*8+j][n=l15]
      f16x8 bph = *(const f16x8*)(tb + l15 * 40 + q4 * 8);
#pragma unroll
      for (int rte = 0; rte < 4; ++rte) {
        f16x8 act = *(const f16x8*)(ctb + (size_t)(l15 + 16 * rte) * 256 + ks2 * 32 + q4 * 8);
        ao[rte] = MFMA16(act, bph, ao[rte]);  // outT: row e, col n (unnormalized)
      }
    }
    dacc += __shfl_xor(dacc, 16, 64);
    dacc += __shfl_xor(dacc, 32, 64);
    float dinv = 1.0f / dacc;
#pragma unroll
    for (int rte = 0; rte < 4; ++rte) {
      float4 o;
      o.x = ao[rte][0] * dinv;
      o.y = ao[rte][1] * dinv;
      o.z = ao[rte][2] * dinv;
      o.w = ao[rte][3] * dinv;
      *(float4*)(obh + (size_t)(n0 + l15) * 64 + rte * 16 + q4 * 4) = o;
    }
  }
}

extern "C" void kernel_launch(void* const* d_in, const int* in_sizes, int n_in,
                              void* d_out, int out_size, void* d_ws, size_t ws_size,
                              hipStream_t stream) {
  const float* q = (const float*)d_in[0];
  const float* k = (const float*)d_in[1];
  const float* v = (const float*)d_in[2];
  const float* proj = (const float*)d_in[3];
  float* out = (float*)d_out;
  float* ws = (float*)d_ws;
  // ws layout (floats): stab[64][8] | kcum[64][256] | ctxT f16[64][64][256]  (~2.07 MB)
  float* ws_stab = ws;                    // 512 floats (1024 reserved)
  float* ws_kcum = ws + 1024;             // 16384 floats
  f16*   ws_ctxT = (f16*)(ws + 17408);    // 1,048,576 f16
  // d_out scratch (67 MB): ctx partials 33.5 MB + kcum partials 0.5 MB; plain stores,
  // fully consumed by K2b before K3 overwrites every element of d_out.
  float* ctx_part  = out;                 // [64][8][256][64] floats
  float* kcum_part = out + 8388608;       // [64][8][256] floats
  k1_stab<<<512, 256, 0, stream>>>(k, proj, ws_stab);
  k2_ctx<<<512, 256, 0, stream>>>(k, v, proj, ws_stab, ctx_part, kcum_part);
  k2b_t<<<256, 256, 0, stream>>>(ctx_part, kcum_part, ws_kcum, ws_ctxT);
  k3_out<<<1024, 256, 0, stream>>>(q, proj, ws_kcum, ws_ctxT, out);
}